// Round 2
// baseline (2331.964 us; speedup 1.0000x reference)
//
#include <hip/hip_runtime.h>
#include <cmath>

#define FEAT 128
#define HID 32
#define NCLASS 16

typedef float4 f4;

__device__ __forceinline__ float dot4(f4 a, f4 b) {
    return a.x * b.x + a.y * b.y + a.z * b.z + a.w * b.w;
}

// h = relu(x @ W_lin^T + b_lin); first = h
__global__ __launch_bounds__(256) void k_lin_relu(
    const float* __restrict__ x, const float* __restrict__ Wl,
    const float* __restrict__ bl, float* __restrict__ h,
    float* __restrict__ first, int N)
{
    int n = blockIdx.x * 256 + threadIdx.x;
    if (n >= N) return;
    const f4* xr = (const f4*)(x + (size_t)n * FEAT);
    const f4* W4 = (const f4*)Wl;  // [HID][FEAT/4] of float4, uniform -> s_load
    float acc[HID];
#pragma unroll
    for (int j = 0; j < HID; ++j) acc[j] = bl[j];
#pragma unroll 4
    for (int k4 = 0; k4 < FEAT / 4; ++k4) {
        f4 xv = xr[k4];
#pragma unroll
        for (int j = 0; j < HID; ++j)
            acc[j] += dot4(xv, W4[j * (FEAT / 4) + k4]);
    }
    f4* hr = (f4*)(h + (size_t)n * HID);
    f4* fr = (f4*)(first + (size_t)n * HID);
#pragma unroll
    for (int j4 = 0; j4 < HID / 4; ++j4) {
        f4 v;
        v.x = fmaxf(acc[j4 * 4 + 0], 0.f);
        v.y = fmaxf(acc[j4 * 4 + 1], 0.f);
        v.z = fmaxf(acc[j4 * 4 + 2], 0.f);
        v.w = fmaxf(acc[j4 * 4 + 3], 0.f);
        hr[j4] = v;
        fr[j4] = v;
    }
}

// agg[dst] += h[src] over all edges; 8 threads per edge, float4 each
__global__ __launch_bounds__(256) void k_scatter(
    const float* __restrict__ h, const int* __restrict__ ei,
    float* agg, int E)
{
    long long tid = (long long)blockIdx.x * 256 + threadIdx.x;
    if (tid >= (long long)E * 8) return;
    int e = (int)(tid >> 3);
    int g = (int)(tid & 7);
    int src = ei[e];
    int dst = ei[(size_t)E + e];
    f4 v = *(const f4*)(h + (size_t)src * HID + g * 4);
    float* ap = agg + (size_t)dst * HID + g * 4;
    unsafeAtomicAdd(ap + 0, v.x);
    unsafeAtomicAdd(ap + 1, v.y);
    unsafeAtomicAdd(ap + 2, v.z);
    unsafeAtomicAdd(ap + 3, v.w);
}

// hout = relu(agg @ Wrel^T + brel + hin @ Wroot^T) + fw[fwidx] * first
// (safe in-place for hin == hout: all reads of a row happen before its writes
//  within the owning thread; no restrict on hin/hout)
__global__ __launch_bounds__(256) void k_combine(
    const float* __restrict__ agg, const float* hin,
    const float* __restrict__ first,
    const float* __restrict__ Wrel, const float* __restrict__ brel,
    const float* __restrict__ Wroot, const float* __restrict__ fw,
    int fwidx, float* hout, int N)
{
    int n = blockIdx.x * 256 + threadIdx.x;
    if (n >= N) return;
    const f4* ar = (const f4*)(agg + (size_t)n * HID);
    const f4* hr = (const f4*)(hin + (size_t)n * HID);
    const f4* fr = (const f4*)(first + (size_t)n * HID);
    const f4* Wr4 = (const f4*)Wrel;   // [32][8] f4, uniform -> s_load
    const f4* Wo4 = (const f4*)Wroot;
    f4 a[8], hh[8];
#pragma unroll
    for (int i = 0; i < 8; ++i) { a[i] = ar[i]; hh[i] = hr[i]; }
    float fwv = fw[fwidx];
    f4* outr = (f4*)(hout + (size_t)n * HID);
#pragma unroll
    for (int j4 = 0; j4 < 8; ++j4) {
        float o[4];
#pragma unroll
        for (int jj = 0; jj < 4; ++jj) {
            int j = j4 * 4 + jj;
            float s = brel[j];
#pragma unroll
            for (int k4 = 0; k4 < 8; ++k4) {
                s += dot4(a[k4], Wr4[j * 8 + k4]);
                s += dot4(hh[k4], Wo4[j * 8 + k4]);
            }
            o[jj] = fmaxf(s, 0.f);
        }
        f4 fv = fr[j4];
        f4 res;
        res.x = o[0] + fwv * fv.x;
        res.y = o[1] + fwv * fv.y;
        res.z = o[2] + fwv * fv.z;
        res.w = o[3] + fwv * fv.w;
        outr[j4] = res;
    }
}

// t = relu(agg @ W2rel^T + b2 + hin @ W2root^T) + fw[1]*first
// logits = t @ Wout^T + bout ; out = log_softmax(logits)
__global__ __launch_bounds__(256) void k_combine_head(
    const float* __restrict__ agg, const float* __restrict__ hin,
    const float* __restrict__ first,
    const float* __restrict__ Wrel, const float* __restrict__ brel,
    const float* __restrict__ Wroot, const float* __restrict__ fw,
    const float* __restrict__ Wout, const float* __restrict__ bout,
    float* __restrict__ out, int N)
{
    int n = blockIdx.x * 256 + threadIdx.x;
    if (n >= N) return;
    const f4* ar = (const f4*)(agg + (size_t)n * HID);
    const f4* hr = (const f4*)(hin + (size_t)n * HID);
    const f4* fr = (const f4*)(first + (size_t)n * HID);
    const f4* Wr4 = (const f4*)Wrel;
    const f4* Wo4 = (const f4*)Wroot;
    const f4* Wout4 = (const f4*)Wout;  // [16][8] f4
    f4 a[8], hh[8];
#pragma unroll
    for (int i = 0; i < 8; ++i) { a[i] = ar[i]; hh[i] = hr[i]; }
    float fwv = fw[1];
    f4 t4[8];
#pragma unroll
    for (int j4 = 0; j4 < 8; ++j4) {
        float o[4];
#pragma unroll
        for (int jj = 0; jj < 4; ++jj) {
            int j = j4 * 4 + jj;
            float s = brel[j];
#pragma unroll
            for (int k4 = 0; k4 < 8; ++k4) {
                s += dot4(a[k4], Wr4[j * 8 + k4]);
                s += dot4(hh[k4], Wo4[j * 8 + k4]);
            }
            o[jj] = fmaxf(s, 0.f);
        }
        f4 fv = fr[j4];
        t4[j4].x = o[0] + fwv * fv.x;
        t4[j4].y = o[1] + fwv * fv.y;
        t4[j4].z = o[2] + fwv * fv.z;
        t4[j4].w = o[3] + fwv * fv.w;
    }
    float logit[NCLASS];
#pragma unroll
    for (int c = 0; c < NCLASS; ++c) {
        float s = bout[c];
#pragma unroll
        for (int j4 = 0; j4 < 8; ++j4) s += dot4(t4[j4], Wout4[c * 8 + j4]);
        logit[c] = s;
    }
    float m = logit[0];
#pragma unroll
    for (int c = 1; c < NCLASS; ++c) m = fmaxf(m, logit[c]);
    float se = 0.f;
#pragma unroll
    for (int c = 0; c < NCLASS; ++c) se += expf(logit[c] - m);
    float lse = logf(se) + m;
    f4* outr = (f4*)(out + (size_t)n * NCLASS);
#pragma unroll
    for (int c4 = 0; c4 < NCLASS / 4; ++c4) {
        f4 v;
        v.x = logit[c4 * 4 + 0] - lse;
        v.y = logit[c4 * 4 + 1] - lse;
        v.z = logit[c4 * 4 + 2] - lse;
        v.w = logit[c4 * 4 + 3] - lse;
        outr[c4] = v;
    }
}

extern "C" void kernel_launch(void* const* d_in, const int* in_sizes, int n_in,
                              void* d_out, int out_size, void* d_ws, size_t ws_size,
                              hipStream_t stream) {
    const float* x      = (const float*)d_in[0];
    const int*   ei     = (const int*)d_in[1];   // JAX x64 disabled -> int32
    const float* W_lin  = (const float*)d_in[2];
    const float* b_lin  = (const float*)d_in[3];
    const float* W1_rel = (const float*)d_in[4];
    const float* b1_rel = (const float*)d_in[5];
    const float* W1_root= (const float*)d_in[6];
    const float* W2_rel = (const float*)d_in[7];
    const float* b2_rel = (const float*)d_in[8];
    const float* W2_root= (const float*)d_in[9];
    const float* fw     = (const float*)d_in[10];
    const float* W_out  = (const float*)d_in[11];
    const float* b_out  = (const float*)d_in[12];
    float* out = (float*)d_out;

    int N = in_sizes[0] / FEAT;
    int E = in_sizes[1] / 2;

    float* h     = (float*)d_ws;
    float* first = h + (size_t)N * HID;
    float* agg   = first + (size_t)N * HID;
    size_t aggBytes = (size_t)N * HID * sizeof(float);

    int nb = (N + 255) / 256;
    long long sthreads = (long long)E * 8;
    int sb = (int)((sthreads + 255) / 256);

    k_lin_relu<<<nb, 256, 0, stream>>>(x, W_lin, b_lin, h, first, N);

    hipMemsetAsync(agg, 0, aggBytes, stream);
    k_scatter<<<sb, 256, 0, stream>>>(h, ei, agg, E);
    k_combine<<<nb, 256, 0, stream>>>(agg, h, first, W1_rel, b1_rel, W1_root,
                                      fw, 0, h, N);

    hipMemsetAsync(agg, 0, aggBytes, stream);
    k_scatter<<<sb, 256, 0, stream>>>(h, ei, agg, E);
    k_combine_head<<<nb, 256, 0, stream>>>(agg, h, first, W2_rel, b2_rel,
                                           W2_root, fw, W_out, b_out, out, N);
}

// Round 9
// 770.124 us; speedup vs baseline: 3.0280x; 3.0280x over previous
//
#include <hip/hip_runtime.h>
#include <cmath>

#define FEAT 128
#define HID 32
#define NCLASS 16
#define SCAN_BS 256

typedef float4 f4;

__device__ __forceinline__ float dot4(f4 a, f4 b) {
    return a.x * b.x + a.y * b.y + a.z * b.z + a.w * b.w;
}

// h = relu(x @ W_lin^T + b_lin); first = h
__global__ __launch_bounds__(256) void k_lin_relu(
    const float* __restrict__ x, const float* __restrict__ Wl,
    const float* __restrict__ bl, float* __restrict__ h,
    float* __restrict__ first, int N)
{
    int n = blockIdx.x * 256 + threadIdx.x;
    if (n >= N) return;
    const f4* xr = (const f4*)(x + (size_t)n * FEAT);
    const f4* W4 = (const f4*)Wl;  // uniform -> scalar loads
    float acc[HID];
#pragma unroll
    for (int j = 0; j < HID; ++j) acc[j] = bl[j];
#pragma unroll 4
    for (int k4 = 0; k4 < FEAT / 4; ++k4) {
        f4 xv = xr[k4];
#pragma unroll
        for (int j = 0; j < HID; ++j)
            acc[j] += dot4(xv, W4[j * (FEAT / 4) + k4]);
    }
    f4* hr = (f4*)(h + (size_t)n * HID);
    f4* fr = (f4*)(first + (size_t)n * HID);
#pragma unroll
    for (int j4 = 0; j4 < HID / 4; ++j4) {
        f4 v;
        v.x = fmaxf(acc[j4 * 4 + 0], 0.f);
        v.y = fmaxf(acc[j4 * 4 + 1], 0.f);
        v.z = fmaxf(acc[j4 * 4 + 2], 0.f);
        v.w = fmaxf(acc[j4 * 4 + 3], 0.f);
        hr[j4] = v;
        fr[j4] = v;
    }
}

// ---- CSR build ----
__global__ __launch_bounds__(256) void k_hist(
    const int* __restrict__ ei, int* __restrict__ cnt, int E)
{
    int e = blockIdx.x * 256 + threadIdx.x;
    if (e >= E) return;
    atomicAdd(&cnt[ei[(size_t)E + e]], 1);
}

// per-block exclusive scan; block sums out
__global__ __launch_bounds__(SCAN_BS) void k_scan1(
    const int* __restrict__ cnt, int* __restrict__ rs,
    int* __restrict__ bsum, int N)
{
    __shared__ int tmp[SCAN_BS];
    int i = blockIdx.x * SCAN_BS + threadIdx.x;
    int t = threadIdx.x;
    int v = (i < N) ? cnt[i] : 0;
    tmp[t] = v;
    __syncthreads();
#pragma unroll
    for (int off = 1; off < SCAN_BS; off <<= 1) {
        int add = (t >= off) ? tmp[t - off] : 0;
        __syncthreads();
        tmp[t] += add;
        __syncthreads();
    }
    if (i < N) rs[i] = tmp[t] - v;   // exclusive
    if (t == SCAN_BS - 1) bsum[blockIdx.x] = tmp[t];
}

__global__ void k_scan2(int* bsum, int nb)
{
    if (blockIdx.x == 0 && threadIdx.x == 0) {
        int acc = 0;
        for (int b = 0; b < nb; ++b) { int v = bsum[b]; bsum[b] = acc; acc += v; }
    }
}

__global__ __launch_bounds__(SCAN_BS) void k_scan3(
    int* __restrict__ rs, const int* __restrict__ bsum,
    int* __restrict__ cursor, int N, int E)
{
    int i = blockIdx.x * SCAN_BS + threadIdx.x;
    if (i < N) {
        int v = rs[i] + bsum[blockIdx.x];
        rs[i] = v;
        cursor[i] = v;
    }
    if (i == 0) rs[N] = E;
}

__global__ __launch_bounds__(256) void k_bin(
    const int* __restrict__ ei, int* __restrict__ cursor,
    int* __restrict__ col, int E)
{
    int e = blockIdx.x * 256 + threadIdx.x;
    if (e >= E) return;
    int src = ei[e];
    int dst = ei[(size_t)E + e];
    int pos = atomicAdd(&cursor[dst], 1);
    col[pos] = src;
}

// agg[d] = sum_{e in row d} h[col[e]]  — pull mode, no float atomics
__global__ __launch_bounds__(256) void k_gather(
    const float* __restrict__ h, const int* __restrict__ rs,
    const int* __restrict__ col, float* __restrict__ agg, int N)
{
    int tid = blockIdx.x * 256 + threadIdx.x;
    if (tid >= N * 8) return;
    int d = tid >> 3;
    int g = tid & 7;
    int beg = rs[d], end = rs[d + 1];
    const f4* h4 = (const f4*)h;
    f4 acc = make_float4(0.f, 0.f, 0.f, 0.f);
    for (int e = beg; e < end; ++e) {
        int s = col[e];
        f4 v = h4[(size_t)s * 8 + g];
        acc.x += v.x; acc.y += v.y; acc.z += v.z; acc.w += v.w;
    }
    ((f4*)agg)[(size_t)d * 8 + g] = acc;
}

// hout = relu(agg @ Wrel^T + brel + hin @ Wroot^T) + fw[fwidx] * first
__global__ __launch_bounds__(256) void k_combine(
    const float* __restrict__ agg, const float* hin,
    const float* __restrict__ first,
    const float* __restrict__ Wrel, const float* __restrict__ brel,
    const float* __restrict__ Wroot, const float* __restrict__ fw,
    int fwidx, float* hout, int N)
{
    int n = blockIdx.x * 256 + threadIdx.x;
    if (n >= N) return;
    const f4* ar = (const f4*)(agg + (size_t)n * HID);
    const f4* hr = (const f4*)(hin + (size_t)n * HID);
    const f4* fr = (const f4*)(first + (size_t)n * HID);
    const f4* Wr4 = (const f4*)Wrel;
    const f4* Wo4 = (const f4*)Wroot;
    f4 a[8], hh[8];
#pragma unroll
    for (int i = 0; i < 8; ++i) { a[i] = ar[i]; hh[i] = hr[i]; }
    float fwv = fw[fwidx];
    f4* outr = (f4*)(hout + (size_t)n * HID);
#pragma unroll
    for (int j4 = 0; j4 < 8; ++j4) {
        float o[4];
#pragma unroll
        for (int jj = 0; jj < 4; ++jj) {
            int j = j4 * 4 + jj;
            float s = brel[j];
#pragma unroll
            for (int k4 = 0; k4 < 8; ++k4) {
                s += dot4(a[k4], Wr4[j * 8 + k4]);
                s += dot4(hh[k4], Wo4[j * 8 + k4]);
            }
            o[jj] = fmaxf(s, 0.f);
        }
        f4 fv = fr[j4];
        f4 res;
        res.x = o[0] + fwv * fv.x;
        res.y = o[1] + fwv * fv.y;
        res.z = o[2] + fwv * fv.z;
        res.w = o[3] + fwv * fv.w;
        outr[j4] = res;
    }
}

// t = relu(agg @ W2rel^T + b2 + hin @ W2root^T) + fw[1]*first
// logits = t @ Wout^T + bout ; out = log_softmax(logits)
__global__ __launch_bounds__(256) void k_combine_head(
    const float* __restrict__ agg, const float* __restrict__ hin,
    const float* __restrict__ first,
    const float* __restrict__ Wrel, const float* __restrict__ brel,
    const float* __restrict__ Wroot, const float* __restrict__ fw,
    const float* __restrict__ Wout, const float* __restrict__ bout,
    float* __restrict__ out, int N)
{
    int n = blockIdx.x * 256 + threadIdx.x;
    if (n >= N) return;
    const f4* ar = (const f4*)(agg + (size_t)n * HID);
    const f4* hr = (const f4*)(hin + (size_t)n * HID);
    const f4* fr = (const f4*)(first + (size_t)n * HID);
    const f4* Wr4 = (const f4*)Wrel;
    const f4* Wo4 = (const f4*)Wroot;
    const f4* Wout4 = (const f4*)Wout;
    f4 a[8], hh[8];
#pragma unroll
    for (int i = 0; i < 8; ++i) { a[i] = ar[i]; hh[i] = hr[i]; }
    float fwv = fw[1];
    f4 t4[8];
#pragma unroll
    for (int j4 = 0; j4 < 8; ++j4) {
        float o[4];
#pragma unroll
        for (int jj = 0; jj < 4; ++jj) {
            int j = j4 * 4 + jj;
            float s = brel[j];
#pragma unroll
            for (int k4 = 0; k4 < 8; ++k4) {
                s += dot4(a[k4], Wr4[j * 8 + k4]);
                s += dot4(hh[k4], Wo4[j * 8 + k4]);
            }
            o[jj] = fmaxf(s, 0.f);
        }
        f4 fv = fr[j4];
        t4[j4].x = o[0] + fwv * fv.x;
        t4[j4].y = o[1] + fwv * fv.y;
        t4[j4].z = o[2] + fwv * fv.z;
        t4[j4].w = o[3] + fwv * fv.w;
    }
    float logit[NCLASS];
#pragma unroll
    for (int c = 0; c < NCLASS; ++c) {
        float s = bout[c];
#pragma unroll
        for (int j4 = 0; j4 < 8; ++j4) s += dot4(t4[j4], Wout4[c * 8 + j4]);
        logit[c] = s;
    }
    float m = logit[0];
#pragma unroll
    for (int c = 1; c < NCLASS; ++c) m = fmaxf(m, logit[c]);
    float se = 0.f;
#pragma unroll
    for (int c = 0; c < NCLASS; ++c) se += expf(logit[c] - m);
    float lse = logf(se) + m;
    f4* outr = (f4*)(out + (size_t)n * NCLASS);
#pragma unroll
    for (int c4 = 0; c4 < NCLASS / 4; ++c4) {
        f4 v;
        v.x = logit[c4 * 4 + 0] - lse;
        v.y = logit[c4 * 4 + 1] - lse;
        v.z = logit[c4 * 4 + 2] - lse;
        v.w = logit[c4 * 4 + 3] - lse;
        outr[c4] = v;
    }
}

extern "C" void kernel_launch(void* const* d_in, const int* in_sizes, int n_in,
                              void* d_out, int out_size, void* d_ws, size_t ws_size,
                              hipStream_t stream) {
    const float* x      = (const float*)d_in[0];
    const int*   ei     = (const int*)d_in[1];   // int32 (JAX x64 disabled)
    const float* W_lin  = (const float*)d_in[2];
    const float* b_lin  = (const float*)d_in[3];
    const float* W1_rel = (const float*)d_in[4];
    const float* b1_rel = (const float*)d_in[5];
    const float* W1_root= (const float*)d_in[6];
    const float* W2_rel = (const float*)d_in[7];
    const float* b2_rel = (const float*)d_in[8];
    const float* W2_root= (const float*)d_in[9];
    const float* fw     = (const float*)d_in[10];
    const float* W_out  = (const float*)d_in[11];
    const float* b_out  = (const float*)d_in[12];
    float* out = (float*)d_out;

    int N = in_sizes[0] / FEAT;
    int E = in_sizes[1] / 2;

    // workspace layout (16B-aligned chunks)
    char* p = (char*)d_ws;
    float* h     = (float*)p;                 p += (size_t)N * HID * 4;
    float* first = (float*)p;                 p += (size_t)N * HID * 4;
    float* agg   = (float*)p;                 p += (size_t)N * HID * 4;
    int* cnt     = (int*)p;                   p += (size_t)N * 4;
    int* rs      = (int*)p;                   p += ((size_t)N + 4) * 4;  // row_start[N+1]
    int* cursor  = (int*)p;                   p += (size_t)N * 4;
    int* bsum    = (int*)p;                   p += 1024 * 4;
    int* col     = (int*)p;                   p += (size_t)E * 4;

    int nb  = (N + 255) / 256;
    int eb  = (E + 255) / 256;
    int sb  = (N + SCAN_BS - 1) / SCAN_BS;    // scan blocks
    int gb  = (N * 8 + 255) / 256;

    // dense input projection
    k_lin_relu<<<nb, 256, 0, stream>>>(x, W_lin, b_lin, h, first, N);

    // CSR build (once, reused by both layers)
    hipMemsetAsync(cnt, 0, (size_t)N * 4, stream);
    k_hist<<<eb, 256, 0, stream>>>(ei, cnt, E);
    k_scan1<<<sb, SCAN_BS, 0, stream>>>(cnt, rs, bsum, N);
    k_scan2<<<1, 64, 0, stream>>>(bsum, sb);
    k_scan3<<<sb, SCAN_BS, 0, stream>>>(rs, bsum, cursor, N, E);
    k_bin<<<eb, 256, 0, stream>>>(ei, cursor, col, E);

    // layer 1
    k_gather<<<gb, 256, 0, stream>>>(h, rs, col, agg, N);
    k_combine<<<nb, 256, 0, stream>>>(agg, h, first, W1_rel, b1_rel, W1_root,
                                      fw, 0, h, N);
    // layer 2 + head
    k_gather<<<gb, 256, 0, stream>>>(h, rs, col, agg, N);
    k_combine_head<<<nb, 256, 0, stream>>>(agg, h, first, W2_rel, b2_rel,
                                           W2_root, fw, W_out, b_out, out, N);
}